// Round 1
// baseline (8972.531 us; speedup 1.0000x reference)
//
#include <hip/hip_runtime.h>
#include <hip/hip_cooperative_groups.h>

namespace cg = cooperative_groups;

// Problem constants
#define VSZ   32000
#define HSZ   512
#define LSZ   4
#define BSZ   32
#define TSZ   51           // MAX_LEN + 1
#define G4H   2048         // 4*H
#define OUT_LOGITS 52224000  // B*T*V
#define MPAD  1664         // T*B=1632 padded to 26*64

// ws layout (in floats)
#define WS_H2    0          // [2][L][B][H]   131072 floats
#define WS_C     131072     // [L][B][H]      65536 floats
#define WS_XC    196608     // [2][B][H]      32768 floats
#define WS_HTOP  229376     // bf16 [1664][512] = 851968 ushorts = 425984 float-slots
#define WS_WB    655360     // bf16 [32000][512] = 16384000 ushorts

typedef __attribute__((ext_vector_type(8))) short bf16x8;
typedef __attribute__((ext_vector_type(4))) float f32x4;

static __device__ __forceinline__ unsigned short f2bf(float f) {
    unsigned int u = __float_as_uint(f);
    unsigned int r = (u + 0x7FFFu + ((u >> 16) & 1u)) >> 16;   // RNE
    return (unsigned short)r;
}

// ---------------- Kernel C: W_out fp32 -> bf16 ----------------
__global__ __launch_bounds__(256) void convw_kernel(const float* __restrict__ W,
                                                    unsigned short* __restrict__ WB) {
    const int n4 = VSZ * HSZ / 4;  // 4,096,000 float4s
    for (int i = blockIdx.x * 256 + threadIdx.x; i < n4; i += gridDim.x * 256) {
        float4 f = ((const float4*)W)[i];
        ushort4 o;
        o.x = f2bf(f.x); o.y = f2bf(f.y); o.z = f2bf(f.z); o.w = f2bf(f.w);
        ((ushort4*)WB)[i] = o;
    }
}

// ---------------- Kernel A: cooperative LSTM ----------------
// grid = 256 blocks x 256 threads. Block = (j-tile of 8) x (b-group of 8).
// Thread: kh = tid&31 (K split 16 each), jl = tid>>5 (8 j). Register-blocks 8 b.
__global__ __launch_bounds__(256) void lstm_kernel(
    const float* __restrict__ dec_h, const float* __restrict__ dec_c,
    const int* __restrict__ target, const float* __restrict__ emb,
    const float* __restrict__ Wih, const float* __restrict__ Whh,
    const float* __restrict__ bih, const float* __restrict__ bhh,
    float* __restrict__ ws, float* __restrict__ out)
{
    cg::grid_group grid = cg::this_grid();

    float* H2 = ws + WS_H2;
    float* C  = ws + WS_C;
    float* XC = ws + WS_XC;
    unsigned short* HTOP = (unsigned short*)(ws + WS_HTOP);

    const int tid = threadIdx.x;
    const int kh = tid & 31;        // K-split lane
    const int jl = tid >> 5;        // 0..7
    const int jt = blockIdx.x >> 2; // 0..63
    const int bg = blockIdx.x & 3;  // 0..3  (8 b's each)
    const int j  = jt * 8 + jl;     // 0..511

    // LDS: x and h rows for this block's 8 batch elements (stride 516 floats)
    __shared__ float xs[8 * 516];
    __shared__ float hs[8 * 516];

    // ---- init: copy h, c; zero htop pad rows ----
    {
        const int gstride = gridDim.x * blockDim.x;
        int gid = blockIdx.x * blockDim.x + tid;
        for (int i = gid; i < LSZ * BSZ * HSZ; i += gstride) {
            H2[i] = dec_h[i];
            C[i]  = dec_c[i];
        }
        for (int i = gid; i < (MPAD - TSZ * BSZ) * HSZ; i += gstride)
            HTOP[TSZ * BSZ * HSZ + i] = 0;
    }
    grid.sync();

    for (int t = 0; t < TSZ; ++t) {
        const int p = t & 1;
        for (int l = 0; l < LSZ; ++l) {
            // ---- stage x and h into LDS (8 rows x 512 each) ----
            {
                const float4* src_h = (const float4*)(H2 + p * 65536 + l * BSZ * HSZ);
                const float4* emb4 = (const float4*)emb;
                const float4* xc4  = (const float4*)XC;
                for (int f = tid; f < 1024; f += 256) {
                    int bi = f >> 7, kf = f & 127;
                    int b = bg * 8 + bi;
                    float4 xv;
                    if (l == 0) {
                        int tok = (t == 0) ? 0 : target[b * TSZ + (t - 1)];
                        xv = emb4[tok * 128 + kf];
                    } else {
                        xv = xc4[(((l & 1) ^ 1)) * 4096 + b * 128 + kf];
                    }
                    *(float4*)&xs[bi * 516 + kf * 4] = xv;
                    *(float4*)&hs[bi * 516 + kf * 4] = src_h[b * 128 + kf];
                }
            }
            __syncthreads();

            // ---- compute partial gate sums ----
            float acc[4][8];
            #pragma unroll
            for (int g = 0; g < 4; ++g)
                #pragma unroll
                for (int bi = 0; bi < 8; ++bi) acc[g][bi] = 0.f;

            const float* wih_base = Wih + l * G4H * HSZ;
            const float* whh_base = Whh + l * G4H * HSZ;

            #pragma unroll
            for (int k4 = 0; k4 < 4; ++k4) {
                const int bk = k4 * 128 + kh * 4;
                float4 xv[8], hv[8];
                #pragma unroll
                for (int bi = 0; bi < 8; ++bi) {
                    xv[bi] = *(const float4*)&xs[bi * 516 + bk];
                    hv[bi] = *(const float4*)&hs[bi * 516 + bk];
                }
                #pragma unroll
                for (int g = 0; g < 4; ++g) {
                    const float4 wi = *(const float4*)&wih_base[(g * HSZ + j) * HSZ + bk];
                    const float4 wh = *(const float4*)&whh_base[(g * HSZ + j) * HSZ + bk];
                    #pragma unroll
                    for (int bi = 0; bi < 8; ++bi) {
                        acc[g][bi] += wi.x * xv[bi].x + wi.y * xv[bi].y
                                    + wi.z * xv[bi].z + wi.w * xv[bi].w
                                    + wh.x * hv[bi].x + wh.y * hv[bi].y
                                    + wh.z * hv[bi].z + wh.w * hv[bi].w;
                    }
                }
            }

            // ---- reduce over the 32 kh lanes ----
            #pragma unroll
            for (int g = 0; g < 4; ++g)
                #pragma unroll
                for (int bi = 0; bi < 8; ++bi) {
                    float v = acc[g][bi];
                    v += __shfl_xor(v, 1);
                    v += __shfl_xor(v, 2);
                    v += __shfl_xor(v, 4);
                    v += __shfl_xor(v, 8);
                    v += __shfl_xor(v, 16);
                    acc[g][bi] = v;
                }

            // ---- elementwise LSTM cell (one lane per (j, b-group)) ----
            if (kh == 0) {
                const float bi_i = bih[l * G4H + j]          + bhh[l * G4H + j];
                const float bi_f = bih[l * G4H + 512 + j]    + bhh[l * G4H + 512 + j];
                const float bi_g = bih[l * G4H + 1024 + j]   + bhh[l * G4H + 1024 + j];
                const float bi_o = bih[l * G4H + 1536 + j]   + bhh[l * G4H + 1536 + j];
                #pragma unroll
                for (int bi = 0; bi < 8; ++bi) {
                    const int b = bg * 8 + bi;
                    float pi = acc[0][bi] + bi_i;
                    float pf = acc[1][bi] + bi_f;
                    float pg = acc[2][bi] + bi_g;
                    float po = acc[3][bi] + bi_o;
                    float ig = 1.f / (1.f + expf(-pi));
                    float fg = 1.f / (1.f + expf(-pf));
                    float gg = tanhf(pg);
                    float og = 1.f / (1.f + expf(-po));
                    const int ci = (l * BSZ + b) * HSZ + j;
                    float cn = fg * C[ci] + ig * gg;
                    float hn = og * tanhf(cn);
                    C[ci] = fminf(fmaxf(cn, -50.f), 50.f);
                    H2[(1 - p) * 65536 + ci] = fminf(fmaxf(hn, -50.f), 50.f);
                    if (l < 3)
                        XC[(l & 1) * 16384 + b * HSZ + j] = hn;       // pre-clamp
                    else
                        HTOP[(t * BSZ + b) * HSZ + j] = f2bf(hn);     // pre-clamp
                }
            }
            grid.sync();
        }
    }

    // ---- h_fin (already clipped): final buffer is H2[1] since T-1=50 is even ----
    {
        const int gstride = gridDim.x * blockDim.x;
        for (int i = blockIdx.x * blockDim.x + tid; i < LSZ * BSZ * HSZ; i += gstride)
            out[OUT_LOGITS + i] = H2[65536 + i];
    }
}

// ---------------- Kernel B: bf16 MFMA projection (gemm_bt) ----------------
// C[m, v] = sum_k HTOP[m,k] * WB[v,k] + b_out[v];  m = t*32 + b  ->  out[(b*51+t)*V + v]
__global__ __launch_bounds__(256) void proj_kernel(
    const unsigned short* __restrict__ A, const unsigned short* __restrict__ Bm,
    const float* __restrict__ bout, float* __restrict__ out)
{
    __shared__ unsigned short As[64 * 40];
    __shared__ unsigned short Bs[64 * 40];
    const int tid = threadIdx.x;
    const int bn = blockIdx.x;   // 0..499
    const int bm = blockIdx.y;   // 0..25
    const int w = tid >> 6, lane = tid & 63;
    const int lr = lane & 15, lq = lane >> 4;

    f32x4 acc0 = {0.f, 0.f, 0.f, 0.f};
    f32x4 acc1 = {0.f, 0.f, 0.f, 0.f};
    f32x4 acc2 = {0.f, 0.f, 0.f, 0.f};
    f32x4 acc3 = {0.f, 0.f, 0.f, 0.f};

    const int r = tid >> 2, c8 = (tid & 3) * 8;
    const unsigned short* Ag = A + (bm * 64 + r) * HSZ + c8;
    const unsigned short* Bg = Bm + (size_t)(bn * 64 + r) * HSZ + c8;

    for (int kt = 0; kt < 16; ++kt) {
        *(uint4*)&As[r * 40 + c8] = *(const uint4*)(Ag + kt * 32);
        *(uint4*)&Bs[r * 40 + c8] = *(const uint4*)(Bg + kt * 32);
        __syncthreads();
        bf16x8 af = *(const bf16x8*)&As[(w * 16 + lr) * 40 + lq * 8];
        bf16x8 b0 = *(const bf16x8*)&Bs[(0 * 16 + lr) * 40 + lq * 8];
        bf16x8 b1 = *(const bf16x8*)&Bs[(1 * 16 + lr) * 40 + lq * 8];
        bf16x8 b2 = *(const bf16x8*)&Bs[(2 * 16 + lr) * 40 + lq * 8];
        bf16x8 b3 = *(const bf16x8*)&Bs[(3 * 16 + lr) * 40 + lq * 8];
        acc0 = __builtin_amdgcn_mfma_f32_16x16x32_bf16(af, b0, acc0, 0, 0, 0);
        acc1 = __builtin_amdgcn_mfma_f32_16x16x32_bf16(af, b1, acc1, 0, 0, 0);
        acc2 = __builtin_amdgcn_mfma_f32_16x16x32_bf16(af, b2, acc2, 0, 0, 0);
        acc3 = __builtin_amdgcn_mfma_f32_16x16x32_bf16(af, b3, acc3, 0, 0, 0);
        __syncthreads();
    }

    f32x4 accs[4] = {acc0, acc1, acc2, acc3};
    #pragma unroll
    for (int nt = 0; nt < 4; ++nt) {
        const int v = bn * 64 + nt * 16 + lr;
        const float bo = bout[v];
        #pragma unroll
        for (int reg = 0; reg < 4; ++reg) {
            const int m = bm * 64 + w * 16 + lq * 4 + reg;
            if (m < TSZ * BSZ) {
                const int tt = m >> 5, b = m & 31;
                out[(size_t)(b * TSZ + tt) * VSZ + v] = accs[nt][reg] + bo;
            }
        }
    }
}

extern "C" void kernel_launch(void* const* d_in, const int* in_sizes, int n_in,
                              void* d_out, int out_size, void* d_ws, size_t ws_size,
                              hipStream_t stream) {
    const float* dec_h = (const float*)d_in[1];
    const float* dec_c = (const float*)d_in[2];
    const int*   tgt   = (const int*)d_in[3];
    const float* emb   = (const float*)d_in[4];
    const float* Wih   = (const float*)d_in[5];
    const float* Whh   = (const float*)d_in[6];
    const float* bihp  = (const float*)d_in[7];
    const float* bhhp  = (const float*)d_in[8];
    const float* Wout  = (const float*)d_in[9];
    const float* bout  = (const float*)d_in[10];
    float* out = (float*)d_out;
    float* ws  = (float*)d_ws;

    unsigned short* HTOP = (unsigned short*)(ws + WS_HTOP);
    unsigned short* WB   = (unsigned short*)(ws + WS_WB);

    // W_out -> bf16 (independent of recurrence; launched first)
    convw_kernel<<<4096, 256, 0, stream>>>(Wout, WB);

    // cooperative LSTM over all 51 steps
    void* args[] = { (void*)&dec_h, (void*)&dec_c, (void*)&tgt, (void*)&emb,
                     (void*)&Wih, (void*)&Whh, (void*)&bihp, (void*)&bhhp,
                     (void*)&ws, (void*)&out };
    hipLaunchCooperativeKernel(reinterpret_cast<void*>(lstm_kernel),
                               dim3(256), dim3(256), args, 0, stream);

    // batched output projection
    proj_kernel<<<dim3(VSZ / 64, MPAD / 64), 256, 0, stream>>>(HTOP, WB, bout, out);
}

// Round 2
// 4208.170 us; speedup vs baseline: 2.1322x; 2.1322x over previous
//
#include <hip/hip_runtime.h>
#include <hip/hip_cooperative_groups.h>

namespace cg = cooperative_groups;

// Problem constants
#define VSZ   32000
#define HSZ   512
#define LSZ   4
#define BSZ   32
#define TSZ   51            // MAX_LEN + 1
#define OUT_LOGITS 52224000 // B*T*V
#define MPAD  1664          // T*B=1632 padded to 26*64

// ws layout (float offsets)
// XH: ping-pong x|h state, [2][L][1024 k][32 b] floats (k<512 = x, k>=512 = h)
#define WS_XH    0          // 262144 floats
#define WS_HTOP  262144     // bf16 [1664][512] = 851968 ushorts = 425984 float-slots
#define WS_WB    688128     // bf16 [32000][512]

typedef __attribute__((ext_vector_type(8))) short bf16x8;
typedef __attribute__((ext_vector_type(4))) float f32x4;

static __device__ __forceinline__ unsigned short f2bf(float f) {
    unsigned int u = __float_as_uint(f);
    unsigned int r = (u + 0x7FFFu + ((u >> 16) & 1u)) >> 16;   // RNE
    return (unsigned short)r;
}

// ---------------- Kernel C: W_out fp32 -> bf16 ----------------
__global__ __launch_bounds__(256) void convw_kernel(const float* __restrict__ W,
                                                    unsigned short* __restrict__ WB) {
    const int n4 = VSZ * HSZ / 4;  // 4,096,000 float4s
    for (int i = blockIdx.x * 256 + threadIdx.x; i < n4; i += gridDim.x * 256) {
        float4 f = ((const float4*)W)[i];
        ushort4 o;
        o.x = f2bf(f.x); o.y = f2bf(f.y); o.z = f2bf(f.z); o.w = f2bf(f.w);
        ((ushort4*)WB)[i] = o;
    }
}

// ---------------- Kernel A: wavefront-pipelined cooperative LSTM ----------------
// 256 blocks x 512 threads. Block = (layer l = blockIdx>>6, j-tile jt = blockIdx&63).
// Stage s: layer l computes timestep t = s - l (valid 0..50); 54 stages total.
// Thread: b = tid&31, kh = (tid>>5)&1 (x-half vs h-half of K), jl = tid>>6 (wave id).
// Each thread computes 4 gate half-dots for (j = jt*8+jl, b); halves combined with
// shfl_xor(32) (both halves are in the same wave). Cell state c is a register.
// State buffer XH is TRANSPOSED [k][b] so x-loads are single-line broadcasts.
__global__ __launch_bounds__(512) void lstm_kernel(
    const float* __restrict__ dec_h, const float* __restrict__ dec_c,
    const int* __restrict__ target, const float* __restrict__ emb,
    const float* __restrict__ Wih, const float* __restrict__ Whh,
    const float* __restrict__ bih, const float* __restrict__ bhh,
    float* __restrict__ ws, float* __restrict__ out)
{
    cg::grid_group grid = cg::this_grid();

    float* XH = ws + WS_XH;                       // [2][4][1024][32]
    unsigned short* HTOP = (unsigned short*)(ws + WS_HTOP);

    const int tid = threadIdx.x;
    const int b   = tid & 31;
    const int kh  = (tid >> 5) & 1;
    const int jl  = tid >> 6;            // 0..7 == wave index
    const int l   = blockIdx.x >> 6;     // 0..3
    const int jt  = blockIdx.x & 63;     // 0..63
    const int j   = jt * 8 + jl;         // 0..511

    // per-thread fused biases (constant across stages)
    const int rj = l * 2048 + j;
    const float bias0 = bih[rj]          + bhh[rj];
    const float bias1 = bih[rj + 512]    + bhh[rj + 512];
    const float bias2 = bih[rj + 1024]   + bhh[rj + 1024];
    const float bias3 = bih[rj + 1536]   + bhh[rj + 1536];

    // cell state lives in a register (this thread exclusively owns (l, b, j))
    float c_reg = dec_c[(l * 32 + b) * 512 + j];

    // weight rows for this thread's K-half: 4 gate rows, 512 floats each
    const float* W = kh ? Whh : Wih;
    const float* wr0 = W + (size_t)(l * 2048 + j) * 512;
    const float* wr1 = wr0 + 262144;     // +512*512 (gate f)
    const float* wr2 = wr0 + 524288;     // gate g
    const float* wr3 = wr0 + 786432;     // gate o

    // ---- init: XH[1][0][x] = emb[SOS], XH[(l+1)&1][l][h] = dec_h ----
    {
        const int gid = blockIdx.x * 512 + tid;   // 0..131071
        if (gid < 16384) {
            int k = gid >> 5, bb = gid & 31;
            XH[131072 + k * 32 + bb] = emb[k];    // SOS token == 0 -> emb row 0
        }
        if (gid < 65536) {
            int l2 = gid >> 14;
            int rem = gid & 16383;
            int j2 = rem >> 5, b2 = rem & 31;
            XH[((l2 + 1) & 1) * 131072 + l2 * 32768 + (512 + j2) * 32 + b2] =
                dec_h[(l2 * 32 + b2) * 512 + j2];
        }
    }
    grid.sync();

    for (int s = 0; s < 54; ++s) {
        const int pp = (s + 1) & 1;   // read parity  = (s-1)&1
        const int pw = s & 1;         // write parity
        const int t  = s - l;

        // pre-pass: build layer-0 x (embedding of token t_next = s+1) for next stage
        if (s < 50 && tid < 64) {
            int e = blockIdx.x * 64 + tid;        // 0..16383
            int k = e >> 5, bb = e & 31;
            int tok = target[bb * TSZ + s];       // token index for t = s+1
            XH[pw * 131072 + k * 32 + bb] = emb[tok * 512 + k];
        }

        if (t >= 0 && t <= 50) {
            const float* xp = XH + pp * 131072 + l * 32768 + kh * 16384 + b;

            float a0 = 0.f, a1 = 0.f, a2 = 0.f, a3 = 0.f;
            #pragma unroll 4
            for (int k4 = 0; k4 < 128; ++k4) {
                const int kb = k4 * 4;
                float x0 = xp[(kb + 0) * 32];
                float x1 = xp[(kb + 1) * 32];
                float x2 = xp[(kb + 2) * 32];
                float x3 = xp[(kb + 3) * 32];
                float4 w0 = *(const float4*)(wr0 + kb);
                float4 w1 = *(const float4*)(wr1 + kb);
                float4 w2 = *(const float4*)(wr2 + kb);
                float4 w3 = *(const float4*)(wr3 + kb);
                a0 += w0.x * x0; a0 += w0.y * x1; a0 += w0.z * x2; a0 += w0.w * x3;
                a1 += w1.x * x0; a1 += w1.y * x1; a1 += w1.z * x2; a1 += w1.w * x3;
                a2 += w2.x * x0; a2 += w2.y * x1; a2 += w2.z * x2; a2 += w2.w * x3;
                a3 += w3.x * x0; a3 += w3.y * x1; a3 += w3.z * x2; a3 += w3.w * x3;
            }
            // combine x-half and h-half (partner lane is lane^32, same wave)
            a0 += __shfl_xor(a0, 32);
            a1 += __shfl_xor(a1, 32);
            a2 += __shfl_xor(a2, 32);
            a3 += __shfl_xor(a3, 32);

            // LSTM cell (computed redundantly by both halves; stores are split)
            float pi = a0 + bias0, pf = a1 + bias1, pg = a2 + bias2, po = a3 + bias3;
            float ig = 1.f / (1.f + expf(-pi));
            float fg = 1.f / (1.f + expf(-pf));
            float gg = tanhf(pg);
            float og = 1.f / (1.f + expf(-po));
            float cn = fg * c_reg + ig * gg;
            float hn = og * tanhf(cn);                  // pre-clamp h
            c_reg     = fminf(fmaxf(cn, -50.f), 50.f);  // clipped carry
            float hcl = fminf(fmaxf(hn, -50.f), 50.f);  // clipped h carry

            if (kh == 0) {
                // recurrent h input for this layer at t+1 (clipped, per reference)
                XH[pw * 131072 + l * 32768 + (512 + j) * 32 + b] = hcl;
                if (l == 3)
                    HTOP[((t * 32 + b) << 9) + j] = f2bf(hn);   // pre-clamp top h
            } else {
                if (l < 3)
                    XH[pw * 131072 + (l + 1) * 32768 + j * 32 + b] = hn; // pre-clamp x
                if (t == 50)
                    out[OUT_LOGITS + ((l * 32 + b) << 9) + j] = hcl;     // h_fin
            }
        }
        grid.sync();
    }
}

// ---------------- Kernel B: bf16 MFMA projection (gemm_bt) ----------------
// C[m, v] = sum_k HTOP[m,k] * WB[v,k] + b_out[v];  m = t*32 + b  ->  out[(b*51+t)*V + v]
__global__ __launch_bounds__(256) void proj_kernel(
    const unsigned short* __restrict__ A, const unsigned short* __restrict__ Bm,
    const float* __restrict__ bout, float* __restrict__ out)
{
    __shared__ unsigned short As[64 * 40];
    __shared__ unsigned short Bs[64 * 40];
    const int tid = threadIdx.x;
    const int bn = blockIdx.x;   // 0..499
    const int bm = blockIdx.y;   // 0..25
    const int w = tid >> 6, lane = tid & 63;
    const int lr = lane & 15, lq = lane >> 4;

    f32x4 acc0 = {0.f, 0.f, 0.f, 0.f};
    f32x4 acc1 = {0.f, 0.f, 0.f, 0.f};
    f32x4 acc2 = {0.f, 0.f, 0.f, 0.f};
    f32x4 acc3 = {0.f, 0.f, 0.f, 0.f};

    const int r = tid >> 2, c8 = (tid & 3) * 8;
    const unsigned short* Ag = A + (bm * 64 + r) * HSZ + c8;
    const unsigned short* Bg = Bm + (size_t)(bn * 64 + r) * HSZ + c8;

    for (int kt = 0; kt < 16; ++kt) {
        *(uint4*)&As[r * 40 + c8] = *(const uint4*)(Ag + kt * 32);
        *(uint4*)&Bs[r * 40 + c8] = *(const uint4*)(Bg + kt * 32);
        __syncthreads();
        bf16x8 af = *(const bf16x8*)&As[(w * 16 + lr) * 40 + lq * 8];
        bf16x8 b0 = *(const bf16x8*)&Bs[(0 * 16 + lr) * 40 + lq * 8];
        bf16x8 b1 = *(const bf16x8*)&Bs[(1 * 16 + lr) * 40 + lq * 8];
        bf16x8 b2 = *(const bf16x8*)&Bs[(2 * 16 + lr) * 40 + lq * 8];
        bf16x8 b3 = *(const bf16x8*)&Bs[(3 * 16 + lr) * 40 + lq * 8];
        acc0 = __builtin_amdgcn_mfma_f32_16x16x32_bf16(af, b0, acc0, 0, 0, 0);
        acc1 = __builtin_amdgcn_mfma_f32_16x16x32_bf16(af, b1, acc1, 0, 0, 0);
        acc2 = __builtin_amdgcn_mfma_f32_16x16x32_bf16(af, b2, acc2, 0, 0, 0);
        acc3 = __builtin_amdgcn_mfma_f32_16x16x32_bf16(af, b3, acc3, 0, 0, 0);
        __syncthreads();
    }

    f32x4 accs[4] = {acc0, acc1, acc2, acc3};
    #pragma unroll
    for (int nt = 0; nt < 4; ++nt) {
        const int v = bn * 64 + nt * 16 + lr;
        const float bo = bout[v];
        #pragma unroll
        for (int reg = 0; reg < 4; ++reg) {
            const int m = bm * 64 + w * 16 + lq * 4 + reg;
            if (m < TSZ * BSZ) {
                const int tt = m >> 5, bb = m & 31;
                out[(size_t)(bb * TSZ + tt) * VSZ + v] = accs[nt][reg] + bo;
            }
        }
    }
}

extern "C" void kernel_launch(void* const* d_in, const int* in_sizes, int n_in,
                              void* d_out, int out_size, void* d_ws, size_t ws_size,
                              hipStream_t stream) {
    const float* dec_h = (const float*)d_in[1];
    const float* dec_c = (const float*)d_in[2];
    const int*   tgt   = (const int*)d_in[3];
    const float* emb   = (const float*)d_in[4];
    const float* Wih   = (const float*)d_in[5];
    const float* Whh   = (const float*)d_in[6];
    const float* bihp  = (const float*)d_in[7];
    const float* bhhp  = (const float*)d_in[8];
    const float* Wout  = (const float*)d_in[9];
    const float* bout  = (const float*)d_in[10];
    float* out = (float*)d_out;
    float* ws  = (float*)d_ws;

    unsigned short* HTOP = (unsigned short*)(ws + WS_HTOP);
    unsigned short* WB   = (unsigned short*)(ws + WS_WB);

    // W_out -> bf16 (independent of the recurrence)
    convw_kernel<<<4096, 256, 0, stream>>>(Wout, WB);

    // wavefront-pipelined cooperative LSTM (54 stages)
    void* args[] = { (void*)&dec_h, (void*)&dec_c, (void*)&tgt, (void*)&emb,
                     (void*)&Wih, (void*)&Whh, (void*)&bihp, (void*)&bhhp,
                     (void*)&ws, (void*)&out };
    hipLaunchCooperativeKernel(reinterpret_cast<void*>(lstm_kernel),
                               dim3(256), dim3(512), args, 0, stream);

    // batched output projection
    proj_kernel<<<dim3(VSZ / 64, MPAD / 64), 256, 0, stream>>>(HTOP, WB, bout, out);
}